// Round 2
// baseline (45.511 us; speedup 1.0000x reference)
//
#include <hip/hip_runtime.h>

// OuterProductMean on MI355X.
// out[i,j,p] = b2[p] + sum_{c,d} W2[p, c*32+d] * x[i,d] * x[j,c]
//   with x = seq @ W1^T + b1, L=512, IN=256, DM=32, PD=64.
// Factored: Y[i,p,c] = sum_d W2[p,c*32+d]*x[i,d]  (4 MB scratch)
//           out[i,j,p] = b2[p] + sum_c x[j,c]*Y[i,p,c]
// FLOPs drop 34.4 GF -> 1.14 GF; kernel 3 is bound by the 67 MB output write.

static constexpr int LL  = 512;
static constexpr int IND = 256;
static constexpr int DM  = 32;   // DIM_MSA
static constexpr int PD  = 64;   // PAIR_DIM

// ---------------- phase 1: x = seq @ W1^T + b1 -> xg [512][32], xTg [32][512]
__global__ __launch_bounds__(256) void k_proj1(const float* __restrict__ seq,
                                               const float* __restrict__ W1,
                                               const float* __restrict__ b1,
                                               float* __restrict__ xg,
                                               float* __restrict__ xTg) {
  __shared__ float part[8][DM];
  const int i   = blockIdx.x;
  const int t   = threadIdx.x;
  const int d   = t & 31;   // output channel
  const int seg = t >> 5;   // 8-way split of the K=256 dot
  const float* srow = seq + (size_t)i * IND + seg * 32;
  const float* wrow = W1  + (size_t)d * IND + seg * 32;
  float acc = 0.f;
#pragma unroll
  for (int k = 0; k < 32; k += 4) {
    const float4 s4 = *(const float4*)(srow + k);
    const float4 w4 = *(const float4*)(wrow + k);
    acc = fmaf(s4.x, w4.x, acc);
    acc = fmaf(s4.y, w4.y, acc);
    acc = fmaf(s4.z, w4.z, acc);
    acc = fmaf(s4.w, w4.w, acc);
  }
  part[seg][d] = acc;
  __syncthreads();
  if (t < DM) {
    float s = b1[t];
#pragma unroll
    for (int g = 0; g < 8; ++g) s += part[g][t];
    xg[i * DM + t]  = s;
    xTg[t * LL + i] = s;
  }
}

// ---------------- phase 2: Y[i][c][p] = sum_d W2[p][c*32+d] * x[i][d]
// One block handles 4 consecutive i. Yg layout [i][c][p] so phase 3 stages
// it with a straight linear copy.
__global__ __launch_bounds__(256) void k_proj2pre(const float* __restrict__ xg,
                                                  const float* __restrict__ W2,
                                                  float* __restrict__ Yg) {
  __shared__ float xs[4][DM];
  const int i0 = blockIdx.x * 4;
  const int t  = threadIdx.x;
  if (t < 128) xs[t >> 5][t & 31] = xg[i0 * DM + t];
  __syncthreads();
  const int p  = t & 63;
  const int c8 = t >> 6;  // 0..3
#pragma unroll
  for (int cc = 0; cc < 8; ++cc) {
    const int c = c8 * 8 + cc;
    const float* w = W2 + (size_t)p * (DM * DM) + c * DM;  // 32 contiguous floats
    float wv[DM];
#pragma unroll
    for (int q = 0; q < 8; ++q) {
      const float4 v = *(const float4*)(w + q * 4);
      wv[q * 4 + 0] = v.x; wv[q * 4 + 1] = v.y;
      wv[q * 4 + 2] = v.z; wv[q * 4 + 3] = v.w;
    }
#pragma unroll
    for (int ii = 0; ii < 4; ++ii) {
      float a = 0.f;
#pragma unroll
      for (int d = 0; d < 32; ++d) a = fmaf(wv[d], xs[ii][d], a);
      Yg[(size_t)(i0 + ii) * (DM * PD) + c * PD + p] = a;  // coalesced in p
    }
  }
}

// ---------------- phase 3: out[i,j,p] = b2[p] + sum_c xT[c][j] * Ys[c][p]
// Block = (i, half of j). LDS 40KB -> 4 blocks/CU. Thread tile 8j x 8p.
__global__ __launch_bounds__(256) void k_outer(const float* __restrict__ xTg,
                                               const float* __restrict__ Yg,
                                               const float* __restrict__ b2,
                                               float* __restrict__ out) {
  __shared__ __align__(16) float xT[DM][256];  // [c][j_local] 32 KB
  __shared__ __align__(16) float Ys[DM][PD];   // [c][p]        8 KB
  const int bid   = blockIdx.x;
  const int i     = bid >> 1;
  const int jbase = (bid & 1) << 8;  // 0 or 256
  const int t     = threadIdx.x;

  // stage Y_i : 2048 floats = 512 float4, linear copy
  {
    const float4* src = (const float4*)(Yg + (size_t)i * (DM * PD));
    float4* dst = (float4*)&Ys[0][0];
    dst[t]       = src[t];
    dst[t + 256] = src[t + 256];
  }
  // stage xT slice: 32 rows x 256 floats = 2048 float4
  {
    const float4* src = (const float4*)xTg;   // row stride 128 float4
    float4* dst = (float4*)&xT[0][0];
#pragma unroll
    for (int k = 0; k < 8; ++k) {
      const int q   = t + k * 256;
      const int c   = q >> 6;
      const int jl4 = q & 63;
      dst[q] = src[c * 128 + (jbase >> 2) + jl4];
    }
  }
  __syncthreads();

  const int pt = t & 7;
  const int jt = t >> 3;       // 0..31
  const int p0 = pt * 8;
  const int j0 = jt * 8;

  const float4 bA = *(const float4*)(b2 + p0);
  const float4 bB = *(const float4*)(b2 + p0 + 4);

  float acc[8][8];
#pragma unroll
  for (int jj = 0; jj < 8; ++jj) {
    acc[jj][0] = bA.x; acc[jj][1] = bA.y; acc[jj][2] = bA.z; acc[jj][3] = bA.w;
    acc[jj][4] = bB.x; acc[jj][5] = bB.y; acc[jj][6] = bB.z; acc[jj][7] = bB.w;
  }

#pragma unroll 4
  for (int c = 0; c < DM; ++c) {
    const float4 xa = *(const float4*)&xT[c][j0];
    const float4 xb = *(const float4*)&xT[c][j0 + 4];
    const float4 ya = *(const float4*)&Ys[c][p0];
    const float4 yb = *(const float4*)&Ys[c][p0 + 4];
    const float xv[8] = {xa.x, xa.y, xa.z, xa.w, xb.x, xb.y, xb.z, xb.w};
    const float yv[8] = {ya.x, ya.y, ya.z, ya.w, yb.x, yb.y, yb.z, yb.w};
#pragma unroll
    for (int jj = 0; jj < 8; ++jj)
#pragma unroll
      for (int pp = 0; pp < 8; ++pp)
        acc[jj][pp] = fmaf(xv[jj], yv[pp], acc[jj][pp]);
  }

  const int jglob0 = jbase + j0;
#pragma unroll
  for (int jj = 0; jj < 8; ++jj) {
    float* orow = out + ((size_t)i * LL + jglob0 + jj) * PD + p0;
    const float4 oA = {acc[jj][0], acc[jj][1], acc[jj][2], acc[jj][3]};
    const float4 oB = {acc[jj][4], acc[jj][5], acc[jj][6], acc[jj][7]};
    *(float4*)(orow)     = oA;
    *(float4*)(orow + 4) = oB;
  }
}

extern "C" void kernel_launch(void* const* d_in, const int* in_sizes, int n_in,
                              void* d_out, int out_size, void* d_ws, size_t ws_size,
                              hipStream_t stream) {
  const float* seq = (const float*)d_in[0];
  const float* W1  = (const float*)d_in[1];
  const float* b1  = (const float*)d_in[2];
  const float* W2  = (const float*)d_in[3];
  const float* b2  = (const float*)d_in[4];
  float* out = (float*)d_out;

  // ws layout (floats): xg[512*32] | xTg[32*512] | Yg[512*32*64]  => ~4.33 MB
  float* xg  = (float*)d_ws;
  float* xTg = xg + LL * DM;
  float* Yg  = xTg + DM * LL;

  k_proj1<<<LL, 256, 0, stream>>>(seq, W1, b1, xg, xTg);
  k_proj2pre<<<LL / 4, 256, 0, stream>>>(xg, W2, Yg);
  k_outer<<<LL * 2, 256, 0, stream>>>(xTg, Yg, b2, out);
}

// Round 3
// 34.326 us; speedup vs baseline: 1.3259x; 1.3259x over previous
//
#include <hip/hip_runtime.h>

// OuterProductMean on MI355X (gfx950).
// out[i,j,p] = b2[p] + sum_{c,d} W2[p, c*32+d] * x[i,d] * x[j,c],  x = seq@W1^T + b1.
// Factored: Y[i][c][p] = sum_d W2[p][c*32+d] * x[i][d]   (4 MB scratch)
//           out[i,j,p] = b2[p] + sum_c x[j,c] * Y[i][c][p]
// Roofline: 67 MB fp32 output write ~10.6 us + 537 M fp32 FMA ~6.8 us (overlapped).

static constexpr int LL  = 512;
static constexpr int IND = 256;
static constexpr int DM  = 32;   // DIM_MSA
static constexpr int PD  = 64;   // PAIR_DIM

// ---------------- k1: x = seq @ W1^T + b1 -> xg [512][32], xTg [32][512]
__global__ __launch_bounds__(256) void k_proj1(const float* __restrict__ seq,
                                               const float* __restrict__ W1,
                                               const float* __restrict__ b1,
                                               float* __restrict__ xg,
                                               float* __restrict__ xTg) {
  __shared__ float part[8][DM];
  const int i   = blockIdx.x;
  const int t   = threadIdx.x;
  const int d   = t & 31;
  const int seg = t >> 5;
  const float* srow = seq + (size_t)i * IND + seg * 32;
  const float* wrow = W1  + (size_t)d * IND + seg * 32;
  float acc = 0.f;
#pragma unroll
  for (int k = 0; k < 32; k += 4) {
    const float4 s4 = *(const float4*)(srow + k);
    const float4 w4 = *(const float4*)(wrow + k);
    acc = fmaf(s4.x, w4.x, acc);
    acc = fmaf(s4.y, w4.y, acc);
    acc = fmaf(s4.z, w4.z, acc);
    acc = fmaf(s4.w, w4.w, acc);
  }
  part[seg][d] = acc;
  __syncthreads();
  if (t < DM) {
    float s = b1[t];
#pragma unroll
    for (int g = 0; g < 8; ++g) s += part[g][t];
    xg[i * DM + t]  = s;
    xTg[t * LL + i] = s;
  }
}

// ---------------- k2: Y[i][c][p] = sum_d W2[p][c*32+d] * x[i][d]
// Grid: 32 c-blocks x 8 i-chunks of 64. All global traffic coalesced via LDS
// staging (rows padded to 36 floats: 16B-aligned, bank-rotating).
__global__ __launch_bounds__(256) void k_y(const float* __restrict__ xg,
                                           const float* __restrict__ W2,
                                           float* __restrict__ Yg) {
  __shared__ __align__(16) float xs[64][36];
  __shared__ __align__(16) float ws2[64][36];
  const int c     = blockIdx.x & 31;
  const int ibase = (blockIdx.x >> 5) * 64;
  const int t     = threadIdx.x;
  // stage x chunk [64][32]
#pragma unroll
  for (int k = 0; k < 2; ++k) {
    const int idx = t + k * 256;        // 0..511 float4s
    const int il = idx >> 3, d4 = idx & 7;
    const float4 v = *(const float4*)(xg + (size_t)(ibase + il) * DM + d4 * 4);
    *(float4*)&xs[il][d4 * 4] = v;
  }
  // stage W2 slice [64 p][32 d] at column block c (rows 4KB apart, 8 lanes/row)
#pragma unroll
  for (int k = 0; k < 2; ++k) {
    const int idx = t + k * 256;
    const int p = idx >> 3, d4 = idx & 7;
    const float4 v = *(const float4*)(W2 + (size_t)p * (DM * DM) + c * DM + d4 * 4);
    *(float4*)&ws2[p][d4 * 4] = v;
  }
  __syncthreads();
  const int p  = t & 63;
  const int ig = t >> 6;    // 0..3 -> 16 i's each
  float wv[DM];
#pragma unroll
  for (int q = 0; q < 8; ++q) {
    const float4 v = *(const float4*)&ws2[p][q * 4];
    wv[q * 4 + 0] = v.x; wv[q * 4 + 1] = v.y;
    wv[q * 4 + 2] = v.z; wv[q * 4 + 3] = v.w;
  }
#pragma unroll
  for (int il = 0; il < 16; ++il) {
    const int row = ig * 16 + il;
    float a = 0.f;
#pragma unroll
    for (int q = 0; q < 8; ++q) {
      const float4 v = *(const float4*)&xs[row][q * 4];  // broadcast
      a = fmaf(wv[q * 4 + 0], v.x, a);
      a = fmaf(wv[q * 4 + 1], v.y, a);
      a = fmaf(wv[q * 4 + 2], v.z, a);
      a = fmaf(wv[q * 4 + 3], v.w, a);
    }
    Yg[(size_t)(ibase + row) * (DM * PD) + c * PD + p] = a;  // 256B/wave, coalesced
  }
}

// ---------------- k3: out[i,j,p] = b2[p] + sum_c xT[c][j] * Ys[c][p]
// Block: one j-quarter (128 j) x 2 consecutive i. LDS 32KB -> 4-5 blocks/CU.
// Pipelined: Ys double-buffered (load-early/write-late), stores issued after
// the buffer-swap barrier so they drain under the next tile's compute.
struct AccT { float4 lo[4]; float4 hi[4]; };

__device__ __forceinline__ AccT tile_compute(const float* __restrict__ xT,
                                             const float* __restrict__ ys,
                                             float4 bA, float4 bB,
                                             int j0, int pA, int pB) {
  float acc[4][8];
#pragma unroll
  for (int jj = 0; jj < 4; ++jj) {
    acc[jj][0] = bA.x; acc[jj][1] = bA.y; acc[jj][2] = bA.z; acc[jj][3] = bA.w;
    acc[jj][4] = bB.x; acc[jj][5] = bB.y; acc[jj][6] = bB.z; acc[jj][7] = bB.w;
  }
#pragma unroll 4
  for (int c = 0; c < DM; ++c) {
    const float4 xv4 = *(const float4*)(xT + c * 128 + j0);
    const float4 ya  = *(const float4*)(ys + c * PD + pA);
    const float4 yb  = *(const float4*)(ys + c * PD + pB);
    const float xv[4] = {xv4.x, xv4.y, xv4.z, xv4.w};
    const float yv[8] = {ya.x, ya.y, ya.z, ya.w, yb.x, yb.y, yb.z, yb.w};
#pragma unroll
    for (int jj = 0; jj < 4; ++jj)
#pragma unroll
      for (int pp = 0; pp < 8; ++pp)
        acc[jj][pp] = fmaf(xv[jj], yv[pp], acc[jj][pp]);
  }
  AccT r;
#pragma unroll
  for (int jj = 0; jj < 4; ++jj) {
    r.lo[jj] = make_float4(acc[jj][0], acc[jj][1], acc[jj][2], acc[jj][3]);
    r.hi[jj] = make_float4(acc[jj][4], acc[jj][5], acc[jj][6], acc[jj][7]);
  }
  return r;
}

__device__ __forceinline__ void tile_store(const AccT& a, float* __restrict__ obase,
                                           int j0, int pA, int pB) {
#pragma unroll
  for (int jj = 0; jj < 4; ++jj) {
    float* r = obase + (size_t)(j0 + jj) * PD;
    *(float4*)(r + pA) = a.lo[jj];   // dense: 8 lanes x 16B = 128B per row
    *(float4*)(r + pB) = a.hi[jj];
  }
}

__global__ __launch_bounds__(256, 4) void k_outer(const float* __restrict__ xTg,
                                                  const float* __restrict__ Yg,
                                                  const float* __restrict__ b2,
                                                  float* __restrict__ out) {
  __shared__ __align__(16) float xT[DM * 128];
  __shared__ __align__(16) float Ys0[DM * PD];
  __shared__ __align__(16) float Ys1[DM * PD];
  const int bid = blockIdx.x;
  const int q   = bid & 3;          // j-quarter
  const int i0  = (bid >> 2) * 2;   // 2 i's per block
  const int t   = threadIdx.x;

  // stage xT quarter: [32 c][128 j], coalesced
#pragma unroll
  for (int k = 0; k < 4; ++k) {
    const int idx = t + k * 256;              // float4 index 0..1023
    const int c = idx >> 5, j4 = idx & 31;
    const float4 v = *(const float4*)(xTg + (size_t)c * LL + q * 128 + j4 * 4);
    *(float4*)&xT[c * 128 + j4 * 4] = v;
  }
  // stage Ys0 (tile i0): 8KB linear
  {
    const float4* s = (const float4*)(Yg + (size_t)i0 * (DM * PD));
    ((float4*)Ys0)[t]       = s[t];
    ((float4*)Ys0)[t + 256] = s[t + 256];
  }
  // issue tile-1 loads now (write-late into Ys1 after tile-0 compute)
  const float4* s1 = (const float4*)(Yg + (size_t)(i0 + 1) * (DM * PD));
  const float4 n0 = s1[t];
  const float4 n1 = s1[t + 256];

  const int pt = t & 7, jt = t >> 3;   // jt 0..31
  const int j0 = jt * 4;
  const int pA = pt * 4, pB = 32 + pt * 4;
  const float4 bA = *(const float4*)(b2 + pA);
  const float4 bB = *(const float4*)(b2 + pB);

  __syncthreads();

  const AccT a0 = tile_compute(xT, Ys0, bA, bB, j0, pA, pB);

  ((float4*)Ys1)[t]       = n0;     // write-late staging for tile 1
  ((float4*)Ys1)[t + 256] = n1;
  __syncthreads();

  tile_store(a0, out + ((size_t)i0 * LL + q * 128) * PD, j0, pA, pB);  // drains under tile-1 compute

  const AccT a1 = tile_compute(xT, Ys1, bA, bB, j0, pA, pB);
  tile_store(a1, out + ((size_t)(i0 + 1) * LL + q * 128) * PD, j0, pA, pB);
}

extern "C" void kernel_launch(void* const* d_in, const int* in_sizes, int n_in,
                              void* d_out, int out_size, void* d_ws, size_t ws_size,
                              hipStream_t stream) {
  const float* seq = (const float*)d_in[0];
  const float* W1  = (const float*)d_in[1];
  const float* b1  = (const float*)d_in[2];
  const float* W2  = (const float*)d_in[3];
  const float* b2  = (const float*)d_in[4];
  float* out = (float*)d_out;

  // ws layout (floats): xg[512*32] | xTg[32*512] | Yg[512*32*64]  => ~4.33 MB
  float* xg  = (float*)d_ws;
  float* xTg = xg + LL * DM;
  float* Yg  = xTg + DM * LL;

  k_proj1<<<LL, 256, 0, stream>>>(seq, W1, b1, xg, xTg);
  k_y<<<256, 256, 0, stream>>>(xg, W2, Yg);
  k_outer<<<LL * 2, 256, 0, stream>>>(xTg, Yg, b2, out);
}

// Round 4
// 32.156 us; speedup vs baseline: 1.4153x; 1.0675x over previous
//
#include <hip/hip_runtime.h>

// OuterProductMean on MI355X (gfx950).
// out[i,j,p] = b2[p] + sum_{c,d} W2[p, c*32+d] * x[i,d] * x[j,c],  x = seq@W1^T + b1.
// Factored: Y[i][c][p] = sum_d W2[p][c*32+d] * x[i][d]   (4 MB scratch)
//           out[i,j,p] = b2[p] + sum_c x[j,c] * Y[i][c][p]
// Roofline: 67 MB fp32 output write ~10.6 us; 537 M fp32 FMA ~6.8 us (overlapped).
// k3 pipelining is done ACROSS blocks: 1 tile/block, grid 2048 = 2x oversubscribed,
// so store drains of retiring blocks overlap compute of newly launched blocks.

static constexpr int LL  = 512;
static constexpr int IND = 256;
static constexpr int DM  = 32;   // DIM_MSA
static constexpr int PD  = 64;   // PAIR_DIM

// ---------------- k1: x = seq @ W1^T + b1 -> xg [512][32], xTg [32][512]
__global__ __launch_bounds__(256) void k_proj1(const float* __restrict__ seq,
                                               const float* __restrict__ W1,
                                               const float* __restrict__ b1,
                                               float* __restrict__ xg,
                                               float* __restrict__ xTg) {
  __shared__ float part[8][DM];
  const int i   = blockIdx.x;
  const int t   = threadIdx.x;
  const int d   = t & 31;
  const int seg = t >> 5;
  const float* srow = seq + (size_t)i * IND + seg * 32;
  const float* wrow = W1  + (size_t)d * IND + seg * 32;
  float acc = 0.f;
#pragma unroll
  for (int k = 0; k < 32; k += 4) {
    const float4 s4 = *(const float4*)(srow + k);
    const float4 w4 = *(const float4*)(wrow + k);
    acc = fmaf(s4.x, w4.x, acc);
    acc = fmaf(s4.y, w4.y, acc);
    acc = fmaf(s4.z, w4.z, acc);
    acc = fmaf(s4.w, w4.w, acc);
  }
  part[seg][d] = acc;
  __syncthreads();
  if (t < DM) {
    float s = b1[t];
#pragma unroll
    for (int g = 0; g < 8; ++g) s += part[g][t];
    xg[i * DM + t]  = s;
    xTg[t * LL + i] = s;
  }
}

// ---------------- k2: Y[i][c][p] = sum_d W2[p][c*32+d] * x[i][d]
// Grid: 32 c-blocks x 8 i-chunks of 64. All global traffic coalesced via LDS
// staging (rows padded to 36 floats).
__global__ __launch_bounds__(256) void k_y(const float* __restrict__ xg,
                                           const float* __restrict__ W2,
                                           float* __restrict__ Yg) {
  __shared__ __align__(16) float xs[64][36];
  __shared__ __align__(16) float ws2[64][36];
  const int c     = blockIdx.x & 31;
  const int ibase = (blockIdx.x >> 5) * 64;
  const int t     = threadIdx.x;
#pragma unroll
  for (int k = 0; k < 2; ++k) {
    const int idx = t + k * 256;        // 0..511 float4s
    const int il = idx >> 3, d4 = idx & 7;
    const float4 v = *(const float4*)(xg + (size_t)(ibase + il) * DM + d4 * 4);
    *(float4*)&xs[il][d4 * 4] = v;
  }
#pragma unroll
  for (int k = 0; k < 2; ++k) {
    const int idx = t + k * 256;
    const int p = idx >> 3, d4 = idx & 7;
    const float4 v = *(const float4*)(W2 + (size_t)p * (DM * DM) + c * DM + d4 * 4);
    *(float4*)&ws2[p][d4 * 4] = v;
  }
  __syncthreads();
  const int p  = t & 63;
  const int ig = t >> 6;    // 0..3 -> 16 i's each
  float wv[DM];
#pragma unroll
  for (int q = 0; q < 8; ++q) {
    const float4 v = *(const float4*)&ws2[p][q * 4];
    wv[q * 4 + 0] = v.x; wv[q * 4 + 1] = v.y;
    wv[q * 4 + 2] = v.z; wv[q * 4 + 3] = v.w;
  }
#pragma unroll
  for (int il = 0; il < 16; ++il) {
    const int row = ig * 16 + il;
    float a = 0.f;
#pragma unroll
    for (int q = 0; q < 8; ++q) {
      const float4 v = *(const float4*)&xs[row][q * 4];  // broadcast
      a = fmaf(wv[q * 4 + 0], v.x, a);
      a = fmaf(wv[q * 4 + 1], v.y, a);
      a = fmaf(wv[q * 4 + 2], v.z, a);
      a = fmaf(wv[q * 4 + 3], v.w, a);
    }
    Yg[(size_t)(ibase + row) * (DM * PD) + c * PD + p] = a;  // coalesced in p
  }
}

// ---------------- k3: out[i,j,p] = b2[p] + sum_c xT[c][j] * Ys[c][p]
// One tile per block: 1 i x 128 j x all 64 p. LDS 24KB. Grid 2048 = 2x the
// resident set, so retiring blocks' store drains overlap fresh blocks' compute.
__global__ __launch_bounds__(256, 4) void k_outer(const float* __restrict__ xTg,
                                                  const float* __restrict__ Yg,
                                                  const float* __restrict__ b2,
                                                  float* __restrict__ out) {
  __shared__ __align__(16) float xT[DM * 128];  // [c][j_local] 16 KB
  __shared__ __align__(16) float Ys[DM * PD];   // [c][p]        8 KB
  const int bid = blockIdx.x;
  const int q   = bid & 3;     // j-quarter
  const int i   = bid >> 2;
  const int t   = threadIdx.x;

  // stage xT quarter: [32 c][128 j], coalesced (512B per c-row chunk)
#pragma unroll
  for (int k = 0; k < 4; ++k) {
    const int idx = t + k * 256;              // float4 index 0..1023
    const int c = idx >> 5, j4 = idx & 31;
    const float4 v = *(const float4*)(xTg + (size_t)c * LL + q * 128 + j4 * 4);
    *(float4*)&xT[c * 128 + j4 * 4] = v;
  }
  // stage Ys (8 KB linear)
  {
    const float4* s = (const float4*)(Yg + (size_t)i * (DM * PD));
    ((float4*)Ys)[t]       = s[t];
    ((float4*)Ys)[t + 256] = s[t + 256];
  }

  const int pt = t & 7, jt = t >> 3;   // jt 0..31
  const int j0 = jt * 4;
  const int pA = pt * 4, pB = 32 + pt * 4;
  const float4 bA = *(const float4*)(b2 + pA);
  const float4 bB = *(const float4*)(b2 + pB);

  float acc[4][8];
#pragma unroll
  for (int jj = 0; jj < 4; ++jj) {
    acc[jj][0] = bA.x; acc[jj][1] = bA.y; acc[jj][2] = bA.z; acc[jj][3] = bA.w;
    acc[jj][4] = bB.x; acc[jj][5] = bB.y; acc[jj][6] = bB.z; acc[jj][7] = bB.w;
  }

  __syncthreads();

#pragma unroll 4
  for (int c = 0; c < DM; ++c) {
    const float4 xv4 = *(const float4*)&xT[c * 128 + j0];
    const float4 ya  = *(const float4*)&Ys[c * PD + pA];
    const float4 yb  = *(const float4*)&Ys[c * PD + pB];
    const float xv[4] = {xv4.x, xv4.y, xv4.z, xv4.w};
    const float yv[8] = {ya.x, ya.y, ya.z, ya.w, yb.x, yb.y, yb.z, yb.w};
#pragma unroll
    for (int jj = 0; jj < 4; ++jj)
#pragma unroll
      for (int pp = 0; pp < 8; ++pp)
        acc[jj][pp] = fmaf(xv[jj], yv[pp], acc[jj][pp]);
  }

  float* obase = out + ((size_t)i * LL + q * 128) * PD;
#pragma unroll
  for (int jj = 0; jj < 4; ++jj) {
    float* r = obase + (size_t)(j0 + jj) * PD;
    *(float4*)(r + pA) = make_float4(acc[jj][0], acc[jj][1], acc[jj][2], acc[jj][3]);
    *(float4*)(r + pB) = make_float4(acc[jj][4], acc[jj][5], acc[jj][6], acc[jj][7]);
  }
}

extern "C" void kernel_launch(void* const* d_in, const int* in_sizes, int n_in,
                              void* d_out, int out_size, void* d_ws, size_t ws_size,
                              hipStream_t stream) {
  const float* seq = (const float*)d_in[0];
  const float* W1  = (const float*)d_in[1];
  const float* b1  = (const float*)d_in[2];
  const float* W2  = (const float*)d_in[3];
  const float* b2  = (const float*)d_in[4];
  float* out = (float*)d_out;

  // ws layout (floats): xg[512*32] | xTg[32*512] | Yg[512*32*64]  => ~4.33 MB
  float* xg  = (float*)d_ws;
  float* xTg = xg + LL * DM;
  float* Yg  = xTg + DM * LL;

  k_proj1<<<LL, 256, 0, stream>>>(seq, W1, b1, xg, xTg);
  k_y<<<256, 256, 0, stream>>>(xg, W2, Yg);
  k_outer<<<LL * 4, 256, 0, stream>>>(xTg, Yg, b2, out);
}